// Round 13
// baseline (276.099 us; speedup 1.0000x reference)
//
#include <hip/hip_runtime.h>

// GCN encoder: 2x GCNConv (PyG semantics: self-loops, symmetric norm, aggregate at col)
// x:[100000,256] f32, W1:[256,128], b1:[128], W2:[128,128], b2:[128], edge_index:[2,1600000] int
// out:[100000,128] f32
//
// Pipeline: bucketed CSR build -> GEMM1 (f32->bf16 RNE MFMA, *dinv, CHUNKED bf16 hs) ->
//   aggc1 (feature-chunked gather: chunk=blockIdx%8 pins chunk<->XCD so the 3.2MB chunk
//          is L2-resident; 2 lanes/node; -> chunked bf16 g) ->
//   GEMM2 (chunked bf16 A, *dinv, chunked hs2) -> aggc2 (f32 row-major out).
// h/g layout: [chunk(8)][node][16 feats] bf16 — GEMM t-tile == chunk, so epilogues write it free.

#define NN 100000
#define NH 128
#define NB 196     // buckets: bucket = col >> 9 (512 nodes each)
#define SB 256     // hist/scatter blocks

__device__ __forceinline__ float bf2f(unsigned int u) { return __uint_as_float(u << 16); }
__device__ __forceinline__ unsigned short f2bf(float f) {
    unsigned int u = __float_as_uint(f);
    u = (u + 0x7fffu + ((u >> 16) & 1u)) >> 16;   // RNE
    return (unsigned short)u;
}

// async 16B/lane global->LDS DMA; lds dest = wave-uniform base + lane*16
__device__ __forceinline__ void dma16(const void* g, void* l) {
    __builtin_amdgcn_global_load_lds(
        (const __attribute__((address_space(1))) unsigned int*)g,
        (__attribute__((address_space(3))) unsigned int*)l, 16, 0, 0);
}

// ---------------- bucketed CSR build ----------------
__global__ __launch_bounds__(256) void k_hist(const int* __restrict__ col,
                                              int* __restrict__ blockCnt, int E, int chb) {
    __shared__ int h[NB];
    int t = threadIdx.x, blk = blockIdx.x;
    if (t < NB) h[t] = 0;
    __syncthreads();
    int s = blk * chb, en = min(E, s + chb);
    for (int e = s + t; e < en; e += 256) atomicAdd(&h[col[e] >> 9], 1);
    __syncthreads();
    if (t < NB) blockCnt[t * SB + blk] = h[t];
}

__global__ __launch_bounds__(256) void k_base(const int* __restrict__ blockCnt,
                                              int* __restrict__ base) {
    __shared__ int s[256];
    int t = threadIdx.x;
    int tot = 0;
    if (t < NB)
        for (int j = 0; j < SB; ++j) tot += blockCnt[t * SB + j];
    s[t] = tot;
    __syncthreads();
    for (int off = 1; off < 256; off <<= 1) {
        int v = (t >= off) ? s[t - off] : 0;
        __syncthreads();
        s[t] += v;
        __syncthreads();
    }
    if (t < NB) base[t] = s[t] - tot;
    if (t == NB - 1) base[NB] = s[t];
}

__global__ __launch_bounds__(256) void k_bscan(const int* __restrict__ blockCnt,
                                               const int* __restrict__ base,
                                               int* __restrict__ blockOff) {
    __shared__ int s[256];
    int t = threadIdx.x, b = blockIdx.x;
    int v = blockCnt[b * SB + t];
    s[t] = v;
    __syncthreads();
    for (int off = 1; off < 256; off <<= 1) {
        int u = (t >= off) ? s[t - off] : 0;
        __syncthreads();
        s[t] += u;
        __syncthreads();
    }
    blockOff[b * SB + t] = base[b] + s[t] - v;
}

__global__ __launch_bounds__(256) void k_scatter(const int* __restrict__ row,
                                                 const int* __restrict__ col,
                                                 const int* __restrict__ blockOff,
                                                 unsigned int* __restrict__ pairs,
                                                 int E, int chb) {
    __shared__ int cur[NB];
    __shared__ int bof[NB];
    int t = threadIdx.x, blk = blockIdx.x;
    if (t < NB) {
        cur[t] = 0;
        bof[t] = blockOff[t * SB + blk];
    }
    __syncthreads();
    int s = blk * chb, en = min(E, s + chb);
    for (int e = s + t; e < en; e += 256) {
        int c = col[e];
        int b = c >> 9;
        int r = atomicAdd(&cur[b], 1);
        pairs[bof[b] + r] = (unsigned int)row[e] | ((unsigned int)(c & 511) << 17);
    }
}

__global__ __launch_bounds__(512) void k_bin(const unsigned int* __restrict__ pairs,
                                             const int* __restrict__ base,
                                             unsigned int* __restrict__ csr,
                                             int* __restrict__ offs,
                                             float* __restrict__ dinv, int n) {
    __shared__ int cnt[512];
    __shared__ int s[512];
    int t = threadIdx.x, b = blockIdx.x;
    cnt[t] = 0;
    __syncthreads();
    int e0 = base[b], e1 = base[b + 1];
    for (int i = e0 + t; i < e1; i += 512) atomicAdd(&cnt[pairs[i] >> 17], 1);
    __syncthreads();
    int v = cnt[t];
    int node = b * 512 + t;
    if (node < n) dinv[node] = rsqrtf(1.0f + (float)v);   // deg = 1 (self-loop) + in-degree
    s[t] = v;
    __syncthreads();
    for (int off = 1; off < 512; off <<= 1) {
        int u = (t >= off) ? s[t - off] : 0;
        __syncthreads();
        s[t] += u;
        __syncthreads();
    }
    int excl = s[t] - v;
    if (node <= n) offs[node] = e0 + excl;
    __syncthreads();
    cnt[t] = e0 + excl;    // absolute cursor
    __syncthreads();
    for (int i = e0 + t; i < e1; i += 512) {
        unsigned int p = pairs[i];
        int d = atomicAdd(&cnt[p >> 17], 1);
        csr[d] = p & 0x1FFFFu;
    }
}

// ---------------- W prepass (both): f32 [K][128] -> transposed RNE bf16 [128][K] ----------------
__global__ void k_wprep2(const float* __restrict__ W1, const float* __restrict__ W2,
                         unsigned short* __restrict__ T1, unsigned short* __restrict__ T2) {
    int idx = blockIdx.x * 256 + threadIdx.x;
    if (idx < 256 * 128) {
        int k = idx >> 7, c = idx & 127;
        T1[(size_t)c * 256 + k] = f2bf(W1[idx]);
    } else {
        int j = idx - 256 * 128;
        if (j < 128 * 128) {
            int k = j >> 7, c = j & 127;
            T2[(size_t)c * 128 + k] = f2bf(W2[j]);
        }
    }
}

// ---------------- GEMM1: hs[chunk][row][16](bf16) = (A[M,256](f32) @ W) * dinv[row] ----------------
// A converted to bf16 RNE in-register. Coalesced DMA sources + XOR part-swizzle.
// C written in chunked layout: chunk == t-tile (16 cols each).
template <int K>
__global__ __launch_bounds__(256) void k_gemm_mfma(const float* __restrict__ A,
                                                   const unsigned short* __restrict__ Bt,
                                                   const float* __restrict__ dinv,
                                                   unsigned short* __restrict__ C, int M) {
    using bf16x8 = __attribute__((ext_vector_type(8))) short;
    using f32x4  = __attribute__((ext_vector_type(4))) float;
    constexpr int T = K / 32;
    __shared__ uint4 sA[2][1024];   // [row(128)][part(8)]  f32, 16KB/buf
    __shared__ uint4 sB[2][512];    // [col(128)][part(4)]  bf16, 8KB/buf

    const int lane = threadIdx.x & 63;
    const int wv   = threadIdx.x >> 6;
    const int r    = lane & 15;
    const int kb   = lane >> 4;
    const int rowBase = blockIdx.x * 128;

    auto stage = [&](int ks, int b) {
        const int kk = ks * 32;
#pragma unroll
        for (int c = 0; c < 4; ++c) {
            int sb = wv * 256 + c * 64;         // wave-uniform slot base
            int q  = sb + lane;
            int row = q >> 3, pg = (q & 7) ^ (row & 7);
            int gr = rowBase + row; if (gr >= M) gr = M - 1;
            dma16(A + (size_t)gr * K + kk + pg * 4, &sA[b][sb]);
        }
#pragma unroll
        for (int c = 0; c < 2; ++c) {
            int sb = wv * 128 + c * 64;
            int q  = sb + lane;
            int bc = q >> 2, pg = (q & 3) ^ (bc & 3);
            dma16(Bt + (size_t)bc * K + kk + pg * 8, &sB[b][sb]);
        }
    };

    f32x4 acc[2][8];
#pragma unroll
    for (int m = 0; m < 2; ++m)
#pragma unroll
        for (int t = 0; t < 8; ++t) acc[m][t] = (f32x4){0.f, 0.f, 0.f, 0.f};

    stage(0, 0);
    __syncthreads();
#pragma unroll
    for (int ks = 0; ks < T; ++ks) {
        const int buf = ks & 1;
        if (ks + 1 < T) stage(ks + 1, buf ^ 1);   // prefetch next tile
        bf16x8 ah[2];
#pragma unroll
        for (int m = 0; m < 2; ++m) {
            int rowl = wv * 32 + m * 16 + r;
            int p0 = (2 * kb)     ^ (rowl & 7);
            int p1 = (2 * kb + 1) ^ (rowl & 7);
            uint4 u0 = sA[buf][rowl * 8 + p0];   // k = kb*8 + 0..3
            uint4 u1 = sA[buf][rowl * 8 + p1];   // k = kb*8 + 4..7
            float f[8];
            *(uint4*)&f[0] = u0;
            *(uint4*)&f[4] = u1;
#pragma unroll
            for (int j = 0; j < 8; ++j) ah[m][j] = (short)f2bf(f[j]);
        }
#pragma unroll
        for (int t = 0; t < 8; ++t) {
            int bc = t * 16 + r;
            bf16x8 bh = *(const bf16x8*)&sB[buf][bc * 4 + (kb ^ (bc & 3))];
#pragma unroll
            for (int m = 0; m < 2; ++m)
                acc[m][t] = __builtin_amdgcn_mfma_f32_16x16x32_bf16(ah[m], bh, acc[m][t], 0, 0, 0);
        }
        __syncthreads();
    }
    const int wrow = rowBase + wv * 32;
#pragma unroll
    for (int m = 0; m < 2; ++m) {
#pragma unroll
        for (int q = 0; q < 4; ++q) {
            int orow = wrow + m * 16 + kb * 4 + q;
            if (orow < M) {
                float dv = dinv[orow];
#pragma unroll
                for (int t = 0; t < 8; ++t)
                    C[(size_t)t * M * 16 + (size_t)orow * 16 + r] = f2bf(acc[m][t][q] * dv);
            }
        }
    }
}

// ---------------- GEMM2: hs2[chunk][row][16](bf16) = (g_chunked @ W) * dinv[row] ----------------
// A read from chunked layout [8][M][16]; feat f = ks*32 + pg*8 -> chunk = ks*2+(pg>>1).
template <int K>
__global__ __launch_bounds__(256) void k_gemm_bf16(const unsigned short* __restrict__ A,
                                                   const unsigned short* __restrict__ Bt,
                                                   const float* __restrict__ dinv,
                                                   unsigned short* __restrict__ C, int M) {
    using bf16x8 = __attribute__((ext_vector_type(8))) short;
    using f32x4  = __attribute__((ext_vector_type(4))) float;
    constexpr int T = K / 32;
    __shared__ uint4 sA[2][512];    // [row(128)][part(4)]  bf16
    __shared__ uint4 sB[2][512];    // [col(128)][part(4)]  bf16

    const int lane = threadIdx.x & 63;
    const int wv   = threadIdx.x >> 6;
    const int r    = lane & 15;
    const int kb   = lane >> 4;
    const int rowBase = blockIdx.x * 128;

    auto stage = [&](int ks, int b) {
        const int kk = ks * 32;
#pragma unroll
        for (int c = 0; c < 2; ++c) {
            int sb = wv * 128 + c * 64;
            int q  = sb + lane;
            int row = q >> 2, pg = (q & 3) ^ (row & 3);
            int gr = rowBase + row; if (gr >= M) gr = M - 1;
            int ch = ks * 2 + (pg >> 1);
            dma16(A + (size_t)ch * M * 16 + (size_t)gr * 16 + (pg & 1) * 8, &sA[b][sb]);
        }
#pragma unroll
        for (int c = 0; c < 2; ++c) {
            int sb = wv * 128 + c * 64;
            int q  = sb + lane;
            int bc = q >> 2, pg = (q & 3) ^ (bc & 3);
            dma16(Bt + (size_t)bc * K + kk + pg * 8, &sB[b][sb]);
        }
    };

    f32x4 acc[2][8];
#pragma unroll
    for (int m = 0; m < 2; ++m)
#pragma unroll
        for (int t = 0; t < 8; ++t) acc[m][t] = (f32x4){0.f, 0.f, 0.f, 0.f};

    stage(0, 0);
    __syncthreads();
#pragma unroll
    for (int ks = 0; ks < T; ++ks) {
        const int buf = ks & 1;
        if (ks + 1 < T) stage(ks + 1, buf ^ 1);
        bf16x8 a[2];
#pragma unroll
        for (int m = 0; m < 2; ++m) {
            int rowl = wv * 32 + m * 16 + r;
            a[m] = *(const bf16x8*)&sA[buf][rowl * 4 + (kb ^ (rowl & 3))];
        }
#pragma unroll
        for (int t = 0; t < 8; ++t) {
            int bc = t * 16 + r;
            bf16x8 bh = *(const bf16x8*)&sB[buf][bc * 4 + (kb ^ (bc & 3))];
#pragma unroll
            for (int m = 0; m < 2; ++m)
                acc[m][t] = __builtin_amdgcn_mfma_f32_16x16x32_bf16(a[m], bh, acc[m][t], 0, 0, 0);
        }
        __syncthreads();
    }
    const int wrow = rowBase + wv * 32;
#pragma unroll
    for (int m = 0; m < 2; ++m) {
#pragma unroll
        for (int q = 0; q < 4; ++q) {
            int orow = wrow + m * 16 + kb * 4 + q;
            if (orow < M) {
                float dv = dinv[orow];
#pragma unroll
                for (int t = 0; t < 8; ++t)
                    C[(size_t)t * M * 16 + (size_t)orow * 16 + r] = f2bf(acc[m][t][q] * dv);
            }
        }
    }
}

// ---------------- feature-chunked aggregate ----------------
// For chunk c (16 feats, 32B/node): out16[i] = dinv[i]*(sum_{e:col=i} hs_c[src] + hs_c[i]) + b_c
// chunk = blockIdx % 8 -> (heuristic) all blocks on XCD k share chunk k => 3.2MB L2-resident.
// 2 lanes/node (uint4 = 16B each), 128 nodes/block, edge loop 8x unrolled.
#define ACCC(u)                                              \
    a[0] += bf2f(u.x & 0xffffu); a[1] += bf2f(u.x >> 16);    \
    a[2] += bf2f(u.y & 0xffffu); a[3] += bf2f(u.y >> 16);    \
    a[4] += bf2f(u.z & 0xffffu); a[5] += bf2f(u.z >> 16);    \
    a[6] += bf2f(u.w & 0xffffu); a[7] += bf2f(u.w >> 16);

template <bool RELU, bool BF16OUT>
__global__ __launch_bounds__(256) void k_aggc(const unsigned short* __restrict__ hc,
                                              const float* __restrict__ dinv,
                                              const int* __restrict__ off,
                                              const unsigned int* __restrict__ csr,
                                              const float* __restrict__ bias,
                                              void* __restrict__ outv, int n) {
    int chunk = blockIdx.x & 7;
    int node  = (blockIdx.x >> 3) * 128 + (threadIdx.x >> 1);
    int l2    = threadIdx.x & 1;
    if (node >= n) return;
    const unsigned short* hb = hc + (size_t)chunk * n * 16;
    float di = dinv[node];
    uint4 us = *(const uint4*)(hb + (size_t)node * 16 + l2 * 8);
    float a[8];
    a[0] = bf2f(us.x & 0xffffu); a[1] = bf2f(us.x >> 16);
    a[2] = bf2f(us.y & 0xffffu); a[3] = bf2f(us.y >> 16);
    a[4] = bf2f(us.z & 0xffffu); a[5] = bf2f(us.z >> 16);
    a[6] = bf2f(us.w & 0xffffu); a[7] = bf2f(us.w >> 16);
    int e  = off[node];
    int e1 = off[node + 1];
    for (; e + 8 <= e1; e += 8) {
        unsigned int s0 = csr[e + 0], s1 = csr[e + 1], s2 = csr[e + 2], s3 = csr[e + 3];
        unsigned int s4 = csr[e + 4], s5 = csr[e + 5], s6 = csr[e + 6], s7 = csr[e + 7];
        uint4 u0 = *(const uint4*)(hb + (size_t)s0 * 16 + l2 * 8);
        uint4 u1 = *(const uint4*)(hb + (size_t)s1 * 16 + l2 * 8);
        uint4 u2 = *(const uint4*)(hb + (size_t)s2 * 16 + l2 * 8);
        uint4 u3 = *(const uint4*)(hb + (size_t)s3 * 16 + l2 * 8);
        uint4 u4 = *(const uint4*)(hb + (size_t)s4 * 16 + l2 * 8);
        uint4 u5 = *(const uint4*)(hb + (size_t)s5 * 16 + l2 * 8);
        uint4 u6 = *(const uint4*)(hb + (size_t)s6 * 16 + l2 * 8);
        uint4 u7 = *(const uint4*)(hb + (size_t)s7 * 16 + l2 * 8);
        ACCC(u0) ACCC(u1) ACCC(u2) ACCC(u3) ACCC(u4) ACCC(u5) ACCC(u6) ACCC(u7)
    }
    for (; e + 4 <= e1; e += 4) {
        unsigned int s0 = csr[e + 0], s1 = csr[e + 1], s2 = csr[e + 2], s3 = csr[e + 3];
        uint4 u0 = *(const uint4*)(hb + (size_t)s0 * 16 + l2 * 8);
        uint4 u1 = *(const uint4*)(hb + (size_t)s1 * 16 + l2 * 8);
        uint4 u2 = *(const uint4*)(hb + (size_t)s2 * 16 + l2 * 8);
        uint4 u3 = *(const uint4*)(hb + (size_t)s3 * 16 + l2 * 8);
        ACCC(u0) ACCC(u1) ACCC(u2) ACCC(u3)
    }
    for (; e < e1; ++e) {
        unsigned int s = csr[e];
        uint4 u = *(const uint4*)(hb + (size_t)s * 16 + l2 * 8);
        ACCC(u)
    }
    float4 b0 = *(const float4*)&bias[chunk * 16 + l2 * 8];
    float4 b1 = *(const float4*)&bias[chunk * 16 + l2 * 8 + 4];
    a[0] = a[0] * di + b0.x; a[1] = a[1] * di + b0.y;
    a[2] = a[2] * di + b0.z; a[3] = a[3] * di + b0.w;
    a[4] = a[4] * di + b1.x; a[5] = a[5] * di + b1.y;
    a[6] = a[6] * di + b1.z; a[7] = a[7] * di + b1.w;
    if (RELU) {
#pragma unroll
        for (int j = 0; j < 8; ++j) a[j] = fmaxf(a[j], 0.f);
    }
    if (BF16OUT) {
        uint4 o;
        o.x = (unsigned int)f2bf(a[0]) | ((unsigned int)f2bf(a[1]) << 16);
        o.y = (unsigned int)f2bf(a[2]) | ((unsigned int)f2bf(a[3]) << 16);
        o.z = (unsigned int)f2bf(a[4]) | ((unsigned int)f2bf(a[5]) << 16);
        o.w = (unsigned int)f2bf(a[6]) | ((unsigned int)f2bf(a[7]) << 16);
        *(uint4*)((unsigned short*)outv + (size_t)chunk * n * 16 + (size_t)node * 16 + l2 * 8) = o;
    } else {
        float* op = (float*)outv + (size_t)node * 128 + chunk * 16 + l2 * 8;
        *(float4*)op       = make_float4(a[0], a[1], a[2], a[3]);
        *(float4*)(op + 4) = make_float4(a[4], a[5], a[6], a[7]);
    }
}

extern "C" void kernel_launch(void* const* d_in, const int* in_sizes, int n_in,
                              void* d_out, int out_size, void* d_ws, size_t ws_size,
                              hipStream_t stream) {
    const float* x  = (const float*)d_in[0];
    const float* W1 = (const float*)d_in[1];
    const float* b1 = (const float*)d_in[2];
    const float* W2 = (const float*)d_in[3];
    const float* b2 = (const float*)d_in[4];
    const int*   ei = (const int*)d_in[5];

    const int n = NN;
    const int E = in_sizes[5] / 2;
    const int* row = ei;        // sources
    const int* col = ei + E;    // targets

    char* ws = (char*)d_ws;
    size_t o = 0;
    auto alloc = [&](size_t bytes) {
        void* p = ws + o;
        o = (o + bytes + 255) & ~(size_t)255;
        return p;
    };
    int*            blockCnt = (int*)alloc((size_t)NB * SB * 4);
    int*            blockOff = (int*)alloc((size_t)NB * SB * 4);
    int*            base     = (int*)alloc((size_t)(NB + 1) * 4);
    int*            offs     = (int*)alloc((size_t)(n + 1) * 4);
    float*          dinv     = (float*)alloc((size_t)n * 4);
    unsigned int*   pairs    = (unsigned int*)alloc((size_t)E * 4);
    unsigned int*   csr      = (unsigned int*)alloc((size_t)E * 4);
    unsigned short* bufH     = (unsigned short*)alloc((size_t)n * NH * 2);  // chunked hs
    unsigned short* bufG     = (unsigned short*)alloc((size_t)n * NH * 2);  // chunked g
    unsigned short* wt1      = (unsigned short*)alloc(256 * 128 * 2);
    unsigned short* wt2      = (unsigned short*)alloc(128 * 128 * 2);

    const int chb = (E + SB - 1) / SB;

    // W prepass (both weights, one launch)
    k_wprep2<<<(384 * 128 + 255) / 256, 256, 0, stream>>>(W1, W2, wt1, wt2);

    // bucketed CSR build
    k_hist<<<SB, 256, 0, stream>>>(col, blockCnt, E, chb);
    k_base<<<1, 256, 0, stream>>>(blockCnt, base);
    k_bscan<<<NB, 256, 0, stream>>>(blockCnt, base, blockOff);
    k_scatter<<<SB, 256, 0, stream>>>(row, col, blockOff, pairs, E, chb);
    k_bin<<<NB, 512, 0, stream>>>(pairs, base, csr, offs, dinv, n);

    int aggBlocks  = ((n + 127) / 128) * 8;   // 8 feature chunks
    int gemmBlocks = (n + 127) / 128;
    // layer 1: hs = (x@W1)*dinv (chunked bf16) ; g = relu(dinv*(agg hs)+b1) (chunked bf16)
    k_gemm_mfma<256><<<gemmBlocks, 256, 0, stream>>>(x, wt1, dinv, bufH, n);
    k_aggc<true, true><<<aggBlocks, 256, 0, stream>>>(bufH, dinv, offs, csr, b1, bufG, n);
    // layer 2: hs2 = (g@W2)*dinv (chunked bf16) ; out = dinv*(agg hs2)+b2 (f32 row-major)
    k_gemm_bf16<128><<<gemmBlocks, 256, 0, stream>>>(bufG, wt2, dinv, bufH, n);
    k_aggc<false, false><<<aggBlocks, 256, 0, stream>>>(bufH, dinv, offs, csr, b2, d_out, n);
}

// Round 14
// 225.128 us; speedup vs baseline: 1.2264x; 1.2264x over previous
//
#include <hip/hip_runtime.h>

// GCN encoder: 2x GCNConv (PyG semantics: self-loops, symmetric norm, aggregate at col)
// x:[100000,256] f32, W1:[256,128], b1:[128], W2:[128,128], b2:[128], edge_index:[2,1600000] int
// out:[100000,128] f32
//
// Pipeline: bucketed CSR build -> GEMM1 (f32->bf16 RNE, MFMA, *dinv[row], bf16 out) ->
//   agg1 (16-lane/node gather-sum, *dinv, +b1, relu, bf16 out) ->
//   GEMM2 (bf16 A, *dinv[row], bf16 out) -> agg2 (f32 out).
// (r11 layer2-fusion regressed: gather needs 6250-block TLP. r13 feature-chunking
//  regressed: 8x csr re-read + partial L2 pinning. This is the r12 anchor config.)

#define NN 100000
#define NH 128
#define NB 196     // buckets: bucket = col >> 9 (512 nodes each)
#define SB 256     // hist/scatter blocks

__device__ __forceinline__ float bf2f(unsigned int u) { return __uint_as_float(u << 16); }
__device__ __forceinline__ unsigned short f2bf(float f) {
    unsigned int u = __float_as_uint(f);
    u = (u + 0x7fffu + ((u >> 16) & 1u)) >> 16;   // RNE
    return (unsigned short)u;
}

// async 16B/lane global->LDS DMA; lds dest = wave-uniform base + lane*16
__device__ __forceinline__ void dma16(const void* g, void* l) {
    __builtin_amdgcn_global_load_lds(
        (const __attribute__((address_space(1))) unsigned int*)g,
        (__attribute__((address_space(3))) unsigned int*)l, 16, 0, 0);
}

// ---------------- bucketed CSR build ----------------
__global__ __launch_bounds__(256) void k_hist(const int* __restrict__ col,
                                              int* __restrict__ blockCnt, int E, int chb) {
    __shared__ int h[NB];
    int t = threadIdx.x, blk = blockIdx.x;
    if (t < NB) h[t] = 0;
    __syncthreads();
    int s = blk * chb, en = min(E, s + chb);
    for (int e = s + t; e < en; e += 256) atomicAdd(&h[col[e] >> 9], 1);
    __syncthreads();
    if (t < NB) blockCnt[t * SB + blk] = h[t];
}

__global__ __launch_bounds__(256) void k_base(const int* __restrict__ blockCnt,
                                              int* __restrict__ base) {
    __shared__ int s[256];
    int t = threadIdx.x;
    int tot = 0;
    if (t < NB)
        for (int j = 0; j < SB; ++j) tot += blockCnt[t * SB + j];
    s[t] = tot;
    __syncthreads();
    for (int off = 1; off < 256; off <<= 1) {
        int v = (t >= off) ? s[t - off] : 0;
        __syncthreads();
        s[t] += v;
        __syncthreads();
    }
    if (t < NB) base[t] = s[t] - tot;
    if (t == NB - 1) base[NB] = s[t];
}

__global__ __launch_bounds__(256) void k_bscan(const int* __restrict__ blockCnt,
                                               const int* __restrict__ base,
                                               int* __restrict__ blockOff) {
    __shared__ int s[256];
    int t = threadIdx.x, b = blockIdx.x;
    int v = blockCnt[b * SB + t];
    s[t] = v;
    __syncthreads();
    for (int off = 1; off < 256; off <<= 1) {
        int u = (t >= off) ? s[t - off] : 0;
        __syncthreads();
        s[t] += u;
        __syncthreads();
    }
    blockOff[b * SB + t] = base[b] + s[t] - v;
}

__global__ __launch_bounds__(256) void k_scatter(const int* __restrict__ row,
                                                 const int* __restrict__ col,
                                                 const int* __restrict__ blockOff,
                                                 unsigned int* __restrict__ pairs,
                                                 int E, int chb) {
    __shared__ int cur[NB];
    __shared__ int bof[NB];
    int t = threadIdx.x, blk = blockIdx.x;
    if (t < NB) {
        cur[t] = 0;
        bof[t] = blockOff[t * SB + blk];
    }
    __syncthreads();
    int s = blk * chb, en = min(E, s + chb);
    for (int e = s + t; e < en; e += 256) {
        int c = col[e];
        int b = c >> 9;
        int r = atomicAdd(&cur[b], 1);
        pairs[bof[b] + r] = (unsigned int)row[e] | ((unsigned int)(c & 511) << 17);
    }
}

__global__ __launch_bounds__(512) void k_bin(const unsigned int* __restrict__ pairs,
                                             const int* __restrict__ base,
                                             unsigned int* __restrict__ csr,
                                             int* __restrict__ offs,
                                             float* __restrict__ dinv, int n) {
    __shared__ int cnt[512];
    __shared__ int s[512];
    int t = threadIdx.x, b = blockIdx.x;
    cnt[t] = 0;
    __syncthreads();
    int e0 = base[b], e1 = base[b + 1];
    for (int i = e0 + t; i < e1; i += 512) atomicAdd(&cnt[pairs[i] >> 17], 1);
    __syncthreads();
    int v = cnt[t];
    int node = b * 512 + t;
    if (node < n) dinv[node] = rsqrtf(1.0f + (float)v);   // deg = 1 (self-loop) + in-degree
    s[t] = v;
    __syncthreads();
    for (int off = 1; off < 512; off <<= 1) {
        int u = (t >= off) ? s[t - off] : 0;
        __syncthreads();
        s[t] += u;
        __syncthreads();
    }
    int excl = s[t] - v;
    if (node <= n) offs[node] = e0 + excl;
    __syncthreads();
    cnt[t] = e0 + excl;    // absolute cursor
    __syncthreads();
    for (int i = e0 + t; i < e1; i += 512) {
        unsigned int p = pairs[i];
        int d = atomicAdd(&cnt[p >> 17], 1);
        csr[d] = p & 0x1FFFFu;
    }
}

// ---------------- W prepass (both): f32 [K][128] -> transposed RNE bf16 [128][K] ----------------
__global__ void k_wprep2(const float* __restrict__ W1, const float* __restrict__ W2,
                         unsigned short* __restrict__ T1, unsigned short* __restrict__ T2) {
    int idx = blockIdx.x * 256 + threadIdx.x;
    if (idx < 256 * 128) {
        int k = idx >> 7, c = idx & 127;
        T1[(size_t)c * 256 + k] = f2bf(W1[idx]);
    } else {
        int j = idx - 256 * 128;
        if (j < 128 * 128) {
            int k = j >> 7, c = j & 127;
            T2[(size_t)c * 128 + k] = f2bf(W2[j]);
        }
    }
}

// ---------------- GEMM1: C[M,128](bf16) = (A[M,K](f32) @ W) * dinv[row] ----------------
// A converted to bf16 RNE in-register. Staging: coalesced DMA sources + XOR part-swizzle
// (linear dest, inverse-swizzled source, swizzled read).
template <int K>
__global__ __launch_bounds__(256) void k_gemm_mfma(const float* __restrict__ A,
                                                   const unsigned short* __restrict__ Bt,
                                                   const float* __restrict__ dinv,
                                                   unsigned short* __restrict__ C, int M) {
    using bf16x8 = __attribute__((ext_vector_type(8))) short;
    using f32x4  = __attribute__((ext_vector_type(4))) float;
    constexpr int T = K / 32;
    __shared__ uint4 sA[2][1024];   // [row(128)][part(8)]  f32, 16KB/buf
    __shared__ uint4 sB[2][512];    // [col(128)][part(4)]  bf16, 8KB/buf

    const int lane = threadIdx.x & 63;
    const int wv   = threadIdx.x >> 6;
    const int r    = lane & 15;
    const int kb   = lane >> 4;
    const int rowBase = blockIdx.x * 128;

    auto stage = [&](int ks, int b) {
        const int kk = ks * 32;
#pragma unroll
        for (int c = 0; c < 4; ++c) {
            int sb = wv * 256 + c * 64;         // wave-uniform slot base
            int q  = sb + lane;
            int row = q >> 3, pg = (q & 7) ^ (row & 7);
            int gr = rowBase + row; if (gr >= M) gr = M - 1;
            dma16(A + (size_t)gr * K + kk + pg * 4, &sA[b][sb]);
        }
#pragma unroll
        for (int c = 0; c < 2; ++c) {
            int sb = wv * 128 + c * 64;
            int q  = sb + lane;
            int bc = q >> 2, pg = (q & 3) ^ (bc & 3);
            dma16(Bt + (size_t)bc * K + kk + pg * 8, &sB[b][sb]);
        }
    };

    f32x4 acc[2][8];
#pragma unroll
    for (int m = 0; m < 2; ++m)
#pragma unroll
        for (int t = 0; t < 8; ++t) acc[m][t] = (f32x4){0.f, 0.f, 0.f, 0.f};

    stage(0, 0);
    __syncthreads();
#pragma unroll
    for (int ks = 0; ks < T; ++ks) {
        const int buf = ks & 1;
        if (ks + 1 < T) stage(ks + 1, buf ^ 1);   // prefetch next tile
        bf16x8 ah[2];
#pragma unroll
        for (int m = 0; m < 2; ++m) {
            int rowl = wv * 32 + m * 16 + r;
            int p0 = (2 * kb)     ^ (rowl & 7);
            int p1 = (2 * kb + 1) ^ (rowl & 7);
            uint4 u0 = sA[buf][rowl * 8 + p0];   // k = kb*8 + 0..3
            uint4 u1 = sA[buf][rowl * 8 + p1];   // k = kb*8 + 4..7
            float f[8];
            *(uint4*)&f[0] = u0;
            *(uint4*)&f[4] = u1;
#pragma unroll
            for (int j = 0; j < 8; ++j) ah[m][j] = (short)f2bf(f[j]);
        }
#pragma unroll
        for (int t = 0; t < 8; ++t) {
            int bc = t * 16 + r;
            bf16x8 bh = *(const bf16x8*)&sB[buf][bc * 4 + (kb ^ (bc & 3))];
#pragma unroll
            for (int m = 0; m < 2; ++m)
                acc[m][t] = __builtin_amdgcn_mfma_f32_16x16x32_bf16(ah[m], bh, acc[m][t], 0, 0, 0);
        }
        __syncthreads();
    }
    const int wrow = rowBase + wv * 32;
#pragma unroll
    for (int m = 0; m < 2; ++m) {
#pragma unroll
        for (int q = 0; q < 4; ++q) {
            int orow = wrow + m * 16 + kb * 4 + q;
            if (orow < M) {
                float dv = dinv[orow];
#pragma unroll
                for (int t = 0; t < 8; ++t)
                    C[(size_t)orow * 128 + t * 16 + r] = f2bf(acc[m][t][q] * dv);
            }
        }
    }
}

// ---------------- GEMM2: C[M,128](bf16) = (A[M,K](bf16) @ W) * dinv[row] ----------------
template <int K>
__global__ __launch_bounds__(256) void k_gemm_bf16(const unsigned short* __restrict__ A,
                                                   const unsigned short* __restrict__ Bt,
                                                   const float* __restrict__ dinv,
                                                   unsigned short* __restrict__ C, int M) {
    using bf16x8 = __attribute__((ext_vector_type(8))) short;
    using f32x4  = __attribute__((ext_vector_type(4))) float;
    constexpr int T = K / 32;
    __shared__ uint4 sA[2][512];    // [row(128)][part(4)]  bf16
    __shared__ uint4 sB[2][512];    // [col(128)][part(4)]  bf16

    const int lane = threadIdx.x & 63;
    const int wv   = threadIdx.x >> 6;
    const int r    = lane & 15;
    const int kb   = lane >> 4;
    const int rowBase = blockIdx.x * 128;

    auto stage = [&](int ks, int b) {
        const int kk = ks * 32;
#pragma unroll
        for (int c = 0; c < 2; ++c) {
            int sb = wv * 128 + c * 64;
            int q  = sb + lane;
            int row = q >> 2, pg = (q & 3) ^ (row & 3);
            int gr = rowBase + row; if (gr >= M) gr = M - 1;
            dma16(A + (size_t)gr * K + kk + pg * 8, &sA[b][sb]);
        }
#pragma unroll
        for (int c = 0; c < 2; ++c) {
            int sb = wv * 128 + c * 64;
            int q  = sb + lane;
            int bc = q >> 2, pg = (q & 3) ^ (bc & 3);
            dma16(Bt + (size_t)bc * K + kk + pg * 8, &sB[b][sb]);
        }
    };

    f32x4 acc[2][8];
#pragma unroll
    for (int m = 0; m < 2; ++m)
#pragma unroll
        for (int t = 0; t < 8; ++t) acc[m][t] = (f32x4){0.f, 0.f, 0.f, 0.f};

    stage(0, 0);
    __syncthreads();
#pragma unroll
    for (int ks = 0; ks < T; ++ks) {
        const int buf = ks & 1;
        if (ks + 1 < T) stage(ks + 1, buf ^ 1);
        bf16x8 a[2];
#pragma unroll
        for (int m = 0; m < 2; ++m) {
            int rowl = wv * 32 + m * 16 + r;
            a[m] = *(const bf16x8*)&sA[buf][rowl * 4 + (kb ^ (rowl & 3))];
        }
#pragma unroll
        for (int t = 0; t < 8; ++t) {
            int bc = t * 16 + r;
            bf16x8 bh = *(const bf16x8*)&sB[buf][bc * 4 + (kb ^ (bc & 3))];
#pragma unroll
            for (int m = 0; m < 2; ++m)
                acc[m][t] = __builtin_amdgcn_mfma_f32_16x16x32_bf16(a[m], bh, acc[m][t], 0, 0, 0);
        }
        __syncthreads();
    }
    const int wrow = rowBase + wv * 32;
#pragma unroll
    for (int m = 0; m < 2; ++m) {
#pragma unroll
        for (int q = 0; q < 4; ++q) {
            int orow = wrow + m * 16 + kb * 4 + q;
            if (orow < M) {
                float dv = dinv[orow];
#pragma unroll
                for (int t = 0; t < 8; ++t)
                    C[(size_t)orow * 128 + t * 16 + r] = f2bf(acc[m][t][q] * dv);
            }
        }
    }
}

// ---------------- aggregate ----------------
// out[i] = dinv[i] * (sum_{e: col=i} hs[src_e] + hs[i]) + b   (hs = h*dinv, bf16)
#define ACC8(u)                                              \
    a[0] += bf2f(u.x & 0xffffu); a[1] += bf2f(u.x >> 16);    \
    a[2] += bf2f(u.y & 0xffffu); a[3] += bf2f(u.y >> 16);    \
    a[4] += bf2f(u.z & 0xffffu); a[5] += bf2f(u.z >> 16);    \
    a[6] += bf2f(u.w & 0xffffu); a[7] += bf2f(u.w >> 16);

template <bool RELU, bool BF16OUT>
__global__ __launch_bounds__(256) void k_agg(const unsigned short* __restrict__ hb,
                                             const float* __restrict__ dinv,
                                             const int* __restrict__ off,
                                             const unsigned int* __restrict__ csr,
                                             const float* __restrict__ bias,
                                             void* __restrict__ outv, int n) {
    int gid  = blockIdx.x * 256 + threadIdx.x;
    int node = gid >> 4;
    int lane = gid & 15;
    if (node >= n) return;
    float di = dinv[node];
    uint4 us = *(const uint4*)(hb + ((size_t)node << 7) + lane * 8);
    float a[8];
    a[0] = bf2f(us.x & 0xffffu); a[1] = bf2f(us.x >> 16);
    a[2] = bf2f(us.y & 0xffffu); a[3] = bf2f(us.y >> 16);
    a[4] = bf2f(us.z & 0xffffu); a[5] = bf2f(us.z >> 16);
    a[6] = bf2f(us.w & 0xffffu); a[7] = bf2f(us.w >> 16);
    int e  = off[node];
    int e1 = off[node + 1];
    for (; e + 8 <= e1; e += 8) {
        unsigned int s0 = csr[e + 0], s1 = csr[e + 1], s2 = csr[e + 2], s3 = csr[e + 3];
        unsigned int s4 = csr[e + 4], s5 = csr[e + 5], s6 = csr[e + 6], s7 = csr[e + 7];
        uint4 u0 = *(const uint4*)(hb + ((size_t)s0 << 7) + lane * 8);
        uint4 u1 = *(const uint4*)(hb + ((size_t)s1 << 7) + lane * 8);
        uint4 u2 = *(const uint4*)(hb + ((size_t)s2 << 7) + lane * 8);
        uint4 u3 = *(const uint4*)(hb + ((size_t)s3 << 7) + lane * 8);
        uint4 u4 = *(const uint4*)(hb + ((size_t)s4 << 7) + lane * 8);
        uint4 u5 = *(const uint4*)(hb + ((size_t)s5 << 7) + lane * 8);
        uint4 u6 = *(const uint4*)(hb + ((size_t)s6 << 7) + lane * 8);
        uint4 u7 = *(const uint4*)(hb + ((size_t)s7 << 7) + lane * 8);
        ACC8(u0) ACC8(u1) ACC8(u2) ACC8(u3) ACC8(u4) ACC8(u5) ACC8(u6) ACC8(u7)
    }
    for (; e + 4 <= e1; e += 4) {
        unsigned int s0 = csr[e + 0], s1 = csr[e + 1], s2 = csr[e + 2], s3 = csr[e + 3];
        uint4 u0 = *(const uint4*)(hb + ((size_t)s0 << 7) + lane * 8);
        uint4 u1 = *(const uint4*)(hb + ((size_t)s1 << 7) + lane * 8);
        uint4 u2 = *(const uint4*)(hb + ((size_t)s2 << 7) + lane * 8);
        uint4 u3 = *(const uint4*)(hb + ((size_t)s3 << 7) + lane * 8);
        ACC8(u0) ACC8(u1) ACC8(u2) ACC8(u3)
    }
    for (; e < e1; ++e) {
        unsigned int s = csr[e];
        uint4 u = *(const uint4*)(hb + ((size_t)s << 7) + lane * 8);
        ACC8(u)
    }
    float4 b0 = *(const float4*)&bias[lane * 8];
    float4 b1 = *(const float4*)&bias[lane * 8 + 4];
    a[0] = a[0] * di + b0.x; a[1] = a[1] * di + b0.y;
    a[2] = a[2] * di + b0.z; a[3] = a[3] * di + b0.w;
    a[4] = a[4] * di + b1.x; a[5] = a[5] * di + b1.y;
    a[6] = a[6] * di + b1.z; a[7] = a[7] * di + b1.w;
    if (RELU) {
#pragma unroll
        for (int j = 0; j < 8; ++j) a[j] = fmaxf(a[j], 0.f);
    }
    if (BF16OUT) {
        uint4 o;
        o.x = (unsigned int)f2bf(a[0]) | ((unsigned int)f2bf(a[1]) << 16);
        o.y = (unsigned int)f2bf(a[2]) | ((unsigned int)f2bf(a[3]) << 16);
        o.z = (unsigned int)f2bf(a[4]) | ((unsigned int)f2bf(a[5]) << 16);
        o.w = (unsigned int)f2bf(a[6]) | ((unsigned int)f2bf(a[7]) << 16);
        *(uint4*)((unsigned short*)outv + ((size_t)node << 7) + lane * 8) = o;
    } else {
        float* op = (float*)outv + ((size_t)node << 7) + lane * 8;
        *(float4*)op       = make_float4(a[0], a[1], a[2], a[3]);
        *(float4*)(op + 4) = make_float4(a[4], a[5], a[6], a[7]);
    }
}

extern "C" void kernel_launch(void* const* d_in, const int* in_sizes, int n_in,
                              void* d_out, int out_size, void* d_ws, size_t ws_size,
                              hipStream_t stream) {
    const float* x  = (const float*)d_in[0];
    const float* W1 = (const float*)d_in[1];
    const float* b1 = (const float*)d_in[2];
    const float* W2 = (const float*)d_in[3];
    const float* b2 = (const float*)d_in[4];
    const int*   ei = (const int*)d_in[5];

    const int n = NN;
    const int E = in_sizes[5] / 2;
    const int* row = ei;        // sources
    const int* col = ei + E;    // targets

    char* ws = (char*)d_ws;
    size_t o = 0;
    auto alloc = [&](size_t bytes) {
        void* p = ws + o;
        o = (o + bytes + 255) & ~(size_t)255;
        return p;
    };
    int*            blockCnt = (int*)alloc((size_t)NB * SB * 4);
    int*            blockOff = (int*)alloc((size_t)NB * SB * 4);
    int*            base     = (int*)alloc((size_t)(NB + 1) * 4);
    int*            offs     = (int*)alloc((size_t)(n + 1) * 4);
    float*          dinv     = (float*)alloc((size_t)n * 4);
    unsigned int*   pairs    = (unsigned int*)alloc((size_t)E * 4);
    unsigned int*   csr      = (unsigned int*)alloc((size_t)E * 4);
    unsigned short* bufH     = (unsigned short*)alloc((size_t)n * NH * 2);  // bf16 hs
    unsigned short* bufG     = (unsigned short*)alloc((size_t)n * NH * 2);  // bf16 g
    unsigned short* wt1      = (unsigned short*)alloc(256 * 128 * 2);
    unsigned short* wt2      = (unsigned short*)alloc(128 * 128 * 2);

    const int chb = (E + SB - 1) / SB;

    // W prepass (both weights, one launch)
    k_wprep2<<<(384 * 128 + 255) / 256, 256, 0, stream>>>(W1, W2, wt1, wt2);

    // bucketed CSR build
    k_hist<<<SB, 256, 0, stream>>>(col, blockCnt, E, chb);
    k_base<<<1, 256, 0, stream>>>(blockCnt, base);
    k_bscan<<<NB, 256, 0, stream>>>(blockCnt, base, blockOff);
    k_scatter<<<SB, 256, 0, stream>>>(row, col, blockOff, pairs, E, chb);
    k_bin<<<NB, 512, 0, stream>>>(pairs, base, csr, offs, dinv, n);

    int aggBlocks  = (n + 15) / 16;
    int gemmBlocks = (n + 127) / 128;
    // layer 1: hs = (x@W1)*dinv (bf16) ; g = relu(dinv*(agg hs)+b1) (bf16)
    k_gemm_mfma<256><<<gemmBlocks, 256, 0, stream>>>(x, wt1, dinv, bufH, n);
    k_agg<true, true><<<aggBlocks, 256, 0, stream>>>(bufH, dinv, offs, csr, b1, bufG, n);
    // layer 2: hs = (g@W2)*dinv (bf16) ; out = dinv*(agg hs)+b2 (f32)
    k_gemm_bf16<128><<<gemmBlocks, 256, 0, stream>>>(bufG, wt2, dinv, bufH, n);
    k_agg<false, false><<<aggBlocks, 256, 0, stream>>>(bufH, dinv, offs, csr, b2, d_out, n);
}